// Round 1
// baseline (117.777 us; speedup 1.0000x reference)
//
#include <hip/hip_runtime.h>

// Problem dims (fixed by reference setup_inputs)
#define B_  4
#define C_  3
#define S_  5
#define M_  18
#define HW  45056            // 256*176
#define HW4 (HW/4)           // 11264 float4s per plane/channel
#define SPLIT 4              // blocks per (b,s,m) plane
#define TPB 256
#define CHUNK4 (HW4/SPLIT)   // 2816 float4s per block
#define ITERS (CHUNK4/TPB)   // 11 iterations per thread
#define NPLANE (B_*S_*M_)    // 360

// Per-component accumulate: rescale x,y from [-1,1] to [0,1], then
// accumulate w, w*x, w*y, w*x*x, w*y*y, w*x*y  (raw, normalization deferred)
#define ACC1(WC, XC, YC, c) do { \
    float xs = fmaf((XC), 0.5f, 0.5f); \
    float ys = fmaf((YC), 0.5f, 0.5f); \
    float wx = (WC) * xs; \
    float wy = (WC) * ys; \
    a1[c]  = fmaf((WC), xs, a1[c]); \
    a2[c]  = fmaf((WC), ys, a2[c]); \
    a11[c] = fmaf(wx, xs, a11[c]); \
    a22[c] = fmaf(wy, ys, a22[c]); \
    a12[c] = fmaf(wx, ys, a12[c]); \
  } while (0)

// Kernel A: per-(plane,chunk) partial sums of the 16 weighted moments.
// Writes deterministic per-block partials to ws[bid*16 + j].
__global__ __launch_bounds__(TPB) void moments_kernel(
    const float4* __restrict__ X, const float4* __restrict__ Y,
    const float4* __restrict__ Mk, float* __restrict__ part) {
  int bid   = blockIdx.x;           // [0, NPLANE*SPLIT)
  int plane = bid / SPLIT;          // (b,s,m)
  int chunk = bid - plane * SPLIT;
  int b     = plane / (S_ * M_);

  const float4* mp = Mk + (size_t)plane * HW4;
  const float4* xp = X  + (size_t)b * (C_ * HW4);
  const float4* yp = Y  + (size_t)b * (C_ * HW4);

  int base = chunk * CHUNK4 + (int)threadIdx.x;

  float aW = 0.f;
  float a1[C_], a2[C_], a11[C_], a22[C_], a12[C_];
#pragma unroll
  for (int c = 0; c < C_; ++c) { a1[c]=a2[c]=a11[c]=a22[c]=a12[c]=0.f; }

#pragma unroll
  for (int it = 0; it < ITERS; ++it) {
    int i = base + it * TPB;
    float4 w = mp[i];
    aW += (w.x + w.y) + (w.z + w.w);
#pragma unroll
    for (int c = 0; c < C_; ++c) {
      float4 xv = xp[c * HW4 + i];
      float4 yv = yp[c * HW4 + i];
      ACC1(w.x, xv.x, yv.x, c);
      ACC1(w.y, xv.y, yv.y, c);
      ACC1(w.z, xv.z, yv.z, c);
      ACC1(w.w, xv.w, yv.w, c);
    }
  }

  // Pack 16 values: [0]=msum, then per channel {wx, wy, wxx, wyy, wxy}
  float v[16];
  v[0] = aW;
#pragma unroll
  for (int c = 0; c < C_; ++c) {
    v[1 + c*5 + 0] = a1[c];
    v[1 + c*5 + 1] = a2[c];
    v[1 + c*5 + 2] = a11[c];
    v[1 + c*5 + 3] = a22[c];
    v[1 + c*5 + 4] = a12[c];
  }

  // wave-64 butterfly reduce all 16 values
#pragma unroll
  for (int off = 32; off > 0; off >>= 1) {
#pragma unroll
    for (int j = 0; j < 16; ++j) v[j] += __shfl_xor(v[j], off);
  }

  __shared__ float red[TPB/64][16];
  int lane = threadIdx.x & 63;
  int wv   = threadIdx.x >> 6;
  if (lane == 0) {
#pragma unroll
    for (int j = 0; j < 16; ++j) red[wv][j] = v[j];
  }
  __syncthreads();
  if (threadIdx.x < 16) {
    float s = (red[0][threadIdx.x] + red[1][threadIdx.x]) +
              (red[2][threadIdx.x] + red[3][threadIdx.x]);
    part[(size_t)bid * 16 + threadIdx.x] = s;
  }
}

// Kernel B: tiny epilogue. One block.
__global__ __launch_bounds__(384) void finalize_kernel(
    const float* __restrict__ part, float* __restrict__ out) {
  __shared__ float csS[NPLANE], ssS[NPLANE];
  __shared__ double csb[B_*S_], ssb[B_*S_];
  int t = threadIdx.x;

  if (t < NPLANE) {
    double s[16];
#pragma unroll
    for (int j = 0; j < 16; ++j) s[j] = 0.0;
    for (int ch = 0; ch < SPLIT; ++ch) {
      const float* p = part + (size_t)(t * SPLIT + ch) * 16;
#pragma unroll
      for (int j = 0; j < 16; ++j) s[j] += (double)p[j];
    }
    const double C1d = 1e-4, C2d = 9e-4;
    double inv = 1.0 / (s[0] + 1e-6);
    double csAcc = 0.0, ssAcc = 0.0;
#pragma unroll
    for (int c = 0; c < C_; ++c) {
      double mu1  = s[1 + c*5 + 0] * inv;
      double mu2  = s[1 + c*5 + 1] * inv;
      double mu11 = s[1 + c*5 + 2] * inv;
      double mu22 = s[1 + c*5 + 3] * inv;
      double mu12 = s[1 + c*5 + 4] * inv;
      double m1s = mu1*mu1, m2s = mu2*mu2, m12 = mu1*mu2;
      double sig1  = mu11 - m1s;
      double sig2  = mu22 - m2s;
      double sig12 = mu12 - m12;
      double cs   = (2.0*sig12 + C2d) / (sig1 + sig2 + C2d);
      double ssim = (2.0*m12 + C1d) / (m1s + m2s + C1d) * cs;
      if (cs   < 0.0) cs   = 0.0;
      if (ssim < 0.0) ssim = 0.0;
      csAcc += cs; ssAcc += ssim;
    }
    csS[t] = (float)csAcc;
    ssS[t] = (float)ssAcc;
  }
  __syncthreads();

  if (t < B_*S_) {  // t = b*S_ + s
    double cb = 0.0, sb = 0.0;
    for (int m = 0; m < M_; ++m) { cb += (double)csS[t*M_ + m]; sb += (double)ssS[t*M_ + m]; }
    csb[t] = cb / (double)(M_*C_);
    ssb[t] = sb / (double)(M_*C_);
  }
  __syncthreads();

  if (t == 0) {
    double acc = 0.0;
    for (int b = 0; b < B_; ++b) {
      double p = ssb[b*S_ + (S_-1)];
      for (int s = 0; s < S_-1; ++s) p *= csb[b*S_ + s];
      acc += p;
    }
    out[0] = (float)(acc / (double)B_);
  }
}

extern "C" void kernel_launch(void* const* d_in, const int* in_sizes, int n_in,
                              void* d_out, int out_size, void* d_ws, size_t ws_size,
                              hipStream_t stream) {
  (void)in_sizes; (void)n_in; (void)out_size; (void)ws_size;
  const float4* X  = (const float4*)d_in[0];
  const float4* Y  = (const float4*)d_in[1];
  const float4* Mk = (const float4*)d_in[2];
  float* part = (float*)d_ws;        // NPLANE*SPLIT*16 floats = 92160 B
  float* out  = (float*)d_out;

  hipLaunchKernelGGL(moments_kernel, dim3(NPLANE*SPLIT), dim3(TPB), 0, stream,
                     X, Y, Mk, part);
  hipLaunchKernelGGL(finalize_kernel, dim3(1), dim3(384), 0, stream, part, out);
}